// Round 5
// baseline (225.556 us; speedup 1.0000x reference)
//
#include <hip/hip_runtime.h>
#include <hip/hip_bf16.h>

// Fused pre-LN MHA block: LN -> QKV GEMM -> flash attn -> out-proj + residual.
// All matmuls bf16 MFMA (16x16x32), fp32 accumulate.
//
// Workspace layout (48 MB total):
//   [ 0MB) h      bf16 [4096,1024]
//   [ 8MB) WqkvT  bf16 [3072,1024]
//   [14MB) WoutT  bf16 [1024,1024]
//   [16MB) q      bf16 [B,H,T,64]  (pre-scaled by 0.125*log2e; softmax uses exp2)
//   [24MB) k      bf16 [B,H,T,64]
//   [32MB) vT     bf16 [B,H,64,T]
//   [40MB) attno  bf16 [4096,1024]

#define DINL static __device__ __forceinline__

typedef __attribute__((ext_vector_type(8))) short bf16x8;
typedef __attribute__((ext_vector_type(4))) float f32x4;

DINL float fast_exp2(float x) { return __builtin_amdgcn_exp2f(x); }

DINL unsigned short f2bf(float f) {
  __hip_bfloat16 h = __float2bfloat16(f);
  unsigned short u;
  __builtin_memcpy(&u, &h, 2);
  return u;
}

// cheap round-half-up f32->bf16 (abs err <= 1 ulp; fine at 0.1 threshold)
DINL unsigned int bfbits(float f) {
  unsigned int u;
  __builtin_memcpy(&u, &f, 4);
  return (u + 0x8000u) >> 16;
}

DINL void gload_lds16(const void* g, void* l) {
  // 16B per lane; LDS dest = wave-uniform base + lane*16
  __builtin_amdgcn_global_load_lds((__attribute__((address_space(1))) void*)g,
                                   (__attribute__((address_space(3))) void*)l,
                                   16, 0, 0);
}

// ---------------- LayerNorm (fp32 -> bf16) ----------------
__global__ __launch_bounds__(256)
void ln_kernel(const float* __restrict__ x, const float* __restrict__ gamma,
               const float* __restrict__ beta, unsigned short* __restrict__ h) {
  __shared__ float red[8];
  int row = blockIdx.x;          // 0..4095
  int t = threadIdx.x;           // 0..255, 4 floats each
  float4 v = reinterpret_cast<const float4*>(x + (size_t)row * 1024)[t];
  float s  = v.x + v.y + v.z + v.w;
  float sq = v.x*v.x + v.y*v.y + v.z*v.z + v.w*v.w;
#pragma unroll
  for (int off = 1; off < 64; off <<= 1) {
    s  += __shfl_xor(s, off);
    sq += __shfl_xor(sq, off);
  }
  int wid = t >> 6;
  if ((t & 63) == 0) { red[wid] = s; red[4 + wid] = sq; }
  __syncthreads();
  s  = red[0] + red[1] + red[2] + red[3];
  sq = red[4] + red[5] + red[6] + red[7];
  float mu   = s * (1.0f / 1024.0f);
  float var  = sq * (1.0f / 1024.0f) - mu * mu;
  float rstd = rsqrtf(var + 1e-5f);
  float4 g = reinterpret_cast<const float4*>(gamma)[t];
  float4 b = reinterpret_cast<const float4*>(beta)[t];
  ushort4 o;
  o.x = f2bf((v.x - mu) * rstd * g.x + b.x);
  o.y = f2bf((v.y - mu) * rstd * g.y + b.y);
  o.z = f2bf((v.z - mu) * rstd * g.z + b.z);
  o.w = f2bf((v.w - mu) * rstd * g.w + b.w);
  reinterpret_cast<ushort4*>(h + (size_t)row * 1024)[t] = o;
}

// ---------------- Transpose + cast: src fp32 [R,C] -> dst bf16 [C,R] ----------------
__global__ __launch_bounds__(256)
void transpose_cast_kernel(const float* __restrict__ src, unsigned short* __restrict__ dst,
                           int R, int C) {
  __shared__ float tile[32][33];
  int tx = threadIdx.x & 31, ty = threadIdx.x >> 5;  // 32 x 8
  int c0 = blockIdx.x * 32, r0 = blockIdx.y * 32;
#pragma unroll
  for (int i = 0; i < 4; i++)
    tile[ty + i * 8][tx] = src[(size_t)(r0 + ty + i * 8) * C + c0 + tx];
  __syncthreads();
#pragma unroll
  for (int i = 0; i < 4; i++) {
    int r = ty + i * 8;
    dst[(size_t)(c0 + r) * R + r0 + tx] = f2bf(tile[tx][r]);
  }
}

// ---------------- GEMM: C[M,N] = A[M,K] * Bt[N,K]^T (+epilogue) ----------------
// 128x128 tile, BK=64, 256 threads = 4 waves (2x2 of 64x64), 16x16x32 MFMA.
// LDS kb-major: chunk c = kb*128 + row holds 8 bf16 of row `row`, k-slice kb.
// MODE 0: qkv epilogue (bias, split q/k/vT, q scaled). MODE 1: bias+residual fp32 out.
template <int MODE>
__global__ __launch_bounds__(256)
void gemm128(const unsigned short* __restrict__ A,
             const unsigned short* __restrict__ Bt,
             int K,
             const float* __restrict__ bias,
             unsigned short* __restrict__ qdst, unsigned short* __restrict__ kdst,
             unsigned short* __restrict__ vTdst,
             const float* __restrict__ xres, float* __restrict__ out) {
  __shared__ unsigned short As[8192];  // 16 KB
  __shared__ unsigned short Bs[8192];
  int tid = threadIdx.x, wid = tid >> 6, lane = tid & 63;
  int l15 = lane & 15, l4 = lane >> 4;
  int brow = blockIdx.y * 128, bcol = blockIdx.x * 128;
  int wr = wid >> 1, wc = wid & 1;
  f32x4 acc[4][4] = {};

  for (int kt = 0; kt < K; kt += 64) {
    __syncthreads();
#pragma unroll
    for (int r = 0; r < 4; r++) {
      int c  = wid * 256 + r * 64;   // wave-uniform chunk base
      int cl = c + lane;
      int kb = cl >> 7, row = cl & 127;
      gload_lds16(A  + (size_t)(brow + row) * K + kt + kb * 8, As + c * 8);
      gload_lds16(Bt + (size_t)(bcol + row) * K + kt + kb * 8, Bs + c * 8);
    }
    __syncthreads();
#pragma unroll
    for (int ks = 0; ks < 2; ks++) {
      int kb = ks * 4 + l4;
      bf16x8 af[4], bfr[4];
#pragma unroll
      for (int m = 0; m < 4; m++)
        af[m] = *reinterpret_cast<const bf16x8*>(As + (kb * 128 + wr * 64 + m * 16 + l15) * 8);
#pragma unroll
      for (int n = 0; n < 4; n++)
        bfr[n] = *reinterpret_cast<const bf16x8*>(Bs + (kb * 128 + wc * 64 + n * 16 + l15) * 8);
#pragma unroll
      for (int m = 0; m < 4; m++)
#pragma unroll
        for (int n = 0; n < 4; n++)
          acc[m][n] = __builtin_amdgcn_mfma_f32_16x16x32_bf16(af[m], bfr[n], acc[m][n], 0, 0, 0);
    }
  }

  if (MODE == 0) {
    int sec = bcol >> 10;            // 0=q, 1=k, 2=v  (128-wide tiles never straddle)
    int secbase = sec << 10;
#pragma unroll
    for (int m = 0; m < 4; m++) {
      int row0 = brow + wr * 64 + m * 16 + l4 * 4;
      int b = row0 >> 11, t0 = row0 & 2047;
#pragma unroll
      for (int n = 0; n < 4; n++) {
        int col = (bcol & 1023) + wc * 64 + n * 16 + l15;
        float bv = bias[secbase + col];
        int hh = col >> 6, d = col & 63;
        if (sec == 2) {
          ushort4 pk;
          pk.x = f2bf(acc[m][n][0] + bv);
          pk.y = f2bf(acc[m][n][1] + bv);
          pk.z = f2bf(acc[m][n][2] + bv);
          pk.w = f2bf(acc[m][n][3] + bv);
          *reinterpret_cast<ushort4*>(vTdst + ((size_t)(b * 16 + hh) * 64 + d) * 2048 + t0) = pk;
        } else {
          unsigned short* dst = (sec == 0) ? qdst : kdst;
          // q pre-scaled by 1/sqrt(hd) * log2(e) so attention can use exp2
          float sc = (sec == 0) ? 0.125f * 1.44269504088896f : 1.0f;
#pragma unroll
          for (int j = 0; j < 4; j++)
            dst[((size_t)(b * 16 + hh) * 2048 + t0 + j) * 64 + d] = f2bf((acc[m][n][j] + bv) * sc);
        }
      }
    }
  } else {
#pragma unroll
    for (int m = 0; m < 4; m++) {
      int row0 = brow + wr * 64 + m * 16 + l4 * 4;
#pragma unroll
      for (int n = 0; n < 4; n++) {
        int col = bcol + wc * 64 + n * 16 + l15;
        float bv = bias[col];
#pragma unroll
        for (int j = 0; j < 4; j++) {
          size_t idx = (size_t)(row0 + j) * 1024 + col;
          out[idx] = acc[m][n][j] + bv + xres[idx];
        }
      }
    }
  }
}

// ---------------- Flash attention (barrier-free, register-resident K/V) ----------------
// 512 blocks (XCD-chunked), 4 INDEPENDENT waves x 32 q-rows. KV tiles of 64.
// S^T = mfma(A=K, B=Q), O^T = mfma(A=V^T, B=P^T). K and V frags both read DIRECT
// from global (L2-resident: 512KB/head, 4 heads/XCD = 2MB < 4MB L2). K register-
// double-buffered (next-tile loads issued a full tile ahead); V single-buffered
// (issued at tile top, consumed ~550cyc later). NO __syncthreads in the loop ->
// waves desync, softmax-VALU of one wave overlaps MFMA of another; setprio(1)
// biases the CU scheduler toward MFMA-phase waves (T5).
struct AttCtx {
  const unsigned short* kh;
  const unsigned short* vh;
  unsigned short* ps;            // this wave's 32x64 swizzled P buffer
  int l15, l4, swz;
};

template <bool DONEXT>
DINL void att_tile(const AttCtx& c, int kv0,
                   bf16x8 (&kc)[2][4], bf16x8 (&kn)[2][4],
                   const bf16x8 (&qf)[2][2],
                   f32x4 (&accO)[2][4], float (&mst)[2], float (&lst)[2]) {
  const int T = 2048;
  // V frags for CURRENT tile: V^T[d = n*16+l15][key = ks*32+l4*8 ..+8]
  bf16x8 vf[2][4];
#pragma unroll
  for (int ks = 0; ks < 2; ks++)
#pragma unroll
    for (int n = 0; n < 4; n++)
      vf[ks][n] = *reinterpret_cast<const bf16x8*>(
          c.vh + (size_t)(n * 16 + c.l15) * T + kv0 + ks * 32 + c.l4 * 8);
  // K frags for NEXT tile: K[key = n*16+l15][d = ks*32+l4*8 ..+8]
  if (DONEXT) {
#pragma unroll
    for (int ks = 0; ks < 2; ks++)
#pragma unroll
      for (int n = 0; n < 4; n++)
        kn[ks][n] = *reinterpret_cast<const bf16x8*>(
            c.kh + (size_t)(kv0 + 64 + n * 16 + c.l15) * 64 + ks * 32 + c.l4 * 8);
  }

  // S^T = K Q^T: lane holds S^T[key = n*16 + l4*4 + j][q = l15 + 16m]
  f32x4 s[2][4] = {};
  __builtin_amdgcn_s_setprio(1);
#pragma unroll
  for (int ks = 0; ks < 2; ks++)
#pragma unroll
    for (int n = 0; n < 4; n++)
#pragma unroll
      for (int m = 0; m < 2; m++)
        s[m][n] = __builtin_amdgcn_mfma_f32_16x16x32_bf16(kc[ks][n], qf[m][ks], s[m][n], 0, 0, 0);
  __builtin_amdgcn_s_setprio(0);

  // online softmax: lane owns 16 of 64 key-scores for q-row l15 (per m)
#pragma unroll
  for (int m = 0; m < 2; m++) {
    float mx0 = fmaxf(fmaxf(s[m][0][0], s[m][0][1]), fmaxf(s[m][0][2], s[m][0][3]));
    float mx1 = fmaxf(fmaxf(s[m][1][0], s[m][1][1]), fmaxf(s[m][1][2], s[m][1][3]));
    float mx2 = fmaxf(fmaxf(s[m][2][0], s[m][2][1]), fmaxf(s[m][2][2], s[m][2][3]));
    float mx3 = fmaxf(fmaxf(s[m][3][0], s[m][3][1]), fmaxf(s[m][3][2], s[m][3][3]));
    float mx = fmaxf(fmaxf(mx0, mx1), fmaxf(mx2, mx3));
    mx = fmaxf(mx, __shfl_xor(mx, 16));
    mx = fmaxf(mx, __shfl_xor(mx, 32));
    float mnew = fmaxf(mst[m], mx);
    float a = fast_exp2(mst[m] - mnew);
    float sum = 0.0f;
#pragma unroll
    for (int n = 0; n < 4; n++) {
#pragma unroll
      for (int j = 0; j < 4; j++) {
        float p = fast_exp2(s[m][n][j] - mnew);
        s[m][n][j] = p;
        sum += p;
      }
      unsigned int u0 = bfbits(s[m][n][0]) | (bfbits(s[m][n][1]) << 16);
      unsigned int u1 = bfbits(s[m][n][2]) | (bfbits(s[m][n][3]) << 16);
      // P^T[key = n*16+l4*4 ..+4][q-row] -> Ps[q][key^swz], packed 8B
      *reinterpret_cast<uint2*>(
          &c.ps[(m * 16 + c.l15) * 64 + ((n * 16 + c.l4 * 4) ^ c.swz)]) =
          make_uint2(u0, u1);
    }
    sum += __shfl_xor(sum, 16);
    sum += __shfl_xor(sum, 32);
    lst[m] = lst[m] * a + sum;
    mst[m] = mnew;
#pragma unroll
    for (int n = 0; n < 4; n++)
#pragma unroll
      for (int j = 0; j < 4; j++) accO[m][n][j] *= a;
  }

  // O^T += V^T P^T : B-frag = P^T[key = ks*32+l4*8 ..+8][q = l15+16m]
#pragma unroll
  for (int ks = 0; ks < 2; ks++) {
#pragma unroll
    for (int m = 0; m < 2; m++) {
      bf16x8 pf = *reinterpret_cast<const bf16x8*>(
          &c.ps[(m * 16 + c.l15) * 64 + ((ks * 32 + c.l4 * 8) ^ c.swz)]);
      __builtin_amdgcn_s_setprio(1);
#pragma unroll
      for (int n = 0; n < 4; n++)
        accO[m][n] = __builtin_amdgcn_mfma_f32_16x16x32_bf16(vf[ks][n], pf, accO[m][n], 0, 0, 0);
      __builtin_amdgcn_s_setprio(0);
    }
  }
}

__global__ __launch_bounds__(256, 2)
void attn_kernel(const unsigned short* __restrict__ q,
                 const unsigned short* __restrict__ kk,
                 const unsigned short* __restrict__ vT,
                 unsigned short* __restrict__ o) {
  const int T = 2048;
  __shared__ unsigned short Ps[4][2048];   // 16 KB: per-wave [q 32][key 64 ^ (q&7)<<3]
  int tid = threadIdx.x, wid = tid >> 6, lane = tid & 63;
  int l15 = lane & 15, l4 = lane >> 4;

  // XCD-chunked bijective remap: all 16 q-blocks of a head land on one XCD
  int lin = blockIdx.x;                    // 0..511
  int rl  = (lin & 7) * 64 + (lin >> 3);
  int bx = rl & 15, bh = rl >> 4;
  int q0 = bx * 128 + wid * 32;            // wave's 32 q-rows

  AttCtx c;
  c.kh  = kk + (size_t)bh * T * 64;
  c.vh  = vT + (size_t)bh * 64 * T;
  c.ps  = &Ps[wid][0];
  c.l15 = l15; c.l4 = l4; c.swz = (l15 & 7) << 3;
  const unsigned short* qh = q + (size_t)bh * T * 64;

  // Q B-fragments: lane holds Q[q = q0 + m*16 + l15][d = ks*32 + l4*8 ..+8]
  bf16x8 qf[2][2];
#pragma unroll
  for (int m = 0; m < 2; m++)
#pragma unroll
    for (int ks = 0; ks < 2; ks++)
      qf[m][ks] = *reinterpret_cast<const bf16x8*>(
          qh + (size_t)(q0 + m * 16 + l15) * 64 + ks * 32 + l4 * 8);

  f32x4 accO[2][4] = {};                   // O^T[d = n*16+l4*4+j][q = l15 + 16m]
  float mst[2] = {-1e30f, -1e30f}, lst[2] = {0.0f, 0.0f};

  // prologue: K frags for tile 0
  bf16x8 KA[2][4], KB[2][4];
#pragma unroll
  for (int ks = 0; ks < 2; ks++)
#pragma unroll
    for (int n = 0; n < 4; n++)
      KA[ks][n] = *reinterpret_cast<const bf16x8*>(
          c.kh + (size_t)(n * 16 + l15) * 64 + ks * 32 + l4 * 8);

  for (int kv0 = 0; kv0 < T; kv0 += 128) {
    att_tile<true>(c, kv0, KA, KB, qf, accO, mst, lst);
    if (kv0 + 128 < T)
      att_tile<true>(c, kv0 + 64, KB, KA, qf, accO, mst, lst);
    else
      att_tile<false>(c, kv0 + 64, KB, KA, qf, accO, mst, lst);
  }

  int b = bh >> 4, hh = bh & 15;
#pragma unroll
  for (int m = 0; m < 2; m++) {
    float inv = 1.0f / lst[m];
    int row = q0 + m * 16 + l15;
#pragma unroll
    for (int n = 0; n < 4; n++) {
      ushort4 pk;
      pk.x = f2bf(accO[m][n][0] * inv);
      pk.y = f2bf(accO[m][n][1] * inv);
      pk.z = f2bf(accO[m][n][2] * inv);
      pk.w = f2bf(accO[m][n][3] * inv);
      *reinterpret_cast<ushort4*>(
          &o[(size_t)(b * 2048 + row) * 1024 + hh * 64 + n * 16 + l4 * 4]) = pk;
    }
  }
}

extern "C" void kernel_launch(void* const* d_in, const int* in_sizes, int n_in,
                              void* d_out, int out_size, void* d_ws, size_t ws_size,
                              hipStream_t stream) {
  const float* x     = (const float*)d_in[0];
  const float* W_qkv = (const float*)d_in[1];
  const float* b_qkv = (const float*)d_in[2];
  const float* W_out = (const float*)d_in[3];
  const float* b_out = (const float*)d_in[4];
  const float* gamma = (const float*)d_in[5];
  const float* beta  = (const float*)d_in[6];
  float* out = (float*)d_out;

  char* ws = (char*)d_ws;
  unsigned short* h     = (unsigned short*)(ws);
  unsigned short* WqkvT = (unsigned short*)(ws + (size_t)(8)  * 1024 * 1024);
  unsigned short* WoutT = (unsigned short*)(ws + (size_t)(14) * 1024 * 1024);
  unsigned short* qb    = (unsigned short*)(ws + (size_t)(16) * 1024 * 1024);
  unsigned short* kb    = (unsigned short*)(ws + (size_t)(24) * 1024 * 1024);
  unsigned short* vTb   = (unsigned short*)(ws + (size_t)(32) * 1024 * 1024);
  unsigned short* attno = (unsigned short*)(ws + (size_t)(40) * 1024 * 1024);

  ln_kernel<<<4096, 256, 0, stream>>>(x, gamma, beta, h);
  transpose_cast_kernel<<<dim3(96, 32), 256, 0, stream>>>(W_qkv, WqkvT, 1024, 3072);
  transpose_cast_kernel<<<dim3(32, 32), 256, 0, stream>>>(W_out, WoutT, 1024, 1024);
  gemm128<0><<<dim3(24, 32), 256, 0, stream>>>(h, WqkvT, 1024, b_qkv, qb, kb, vTb, nullptr, nullptr);
  attn_kernel<<<512, 256, 0, stream>>>(qb, kb, vTb, attno);
  gemm128<1><<<dim3(8, 32), 256, 0, stream>>>(attno, WoutT, 1024, b_out, nullptr, nullptr, nullptr, x, out);
}

// Round 6
// 183.227 us; speedup vs baseline: 1.2310x; 1.2310x over previous
//
#include <hip/hip_runtime.h>
#include <hip/hip_bf16.h>

// Fused pre-LN MHA block: LN -> QKV GEMM -> flash attn -> out-proj + residual.
// All matmuls bf16 MFMA (16x16x32), fp32 accumulate.
//
// Workspace layout (48 MB total):
//   [ 0MB) h      bf16 [4096,1024]
//   [ 8MB) WqkvT  bf16 [3072,1024]
//   [14MB) WoutT  bf16 [1024,1024]
//   [16MB) q      bf16 [B,H,T,64]  (pre-scaled by 0.125*log2e; softmax uses exp2)
//   [24MB) k      bf16 [B,H,T,64]
//   [32MB) vT     bf16 [B,H,64,T]
//   [40MB) attno  bf16 [4096,1024]

#define DINL static __device__ __forceinline__

typedef __attribute__((ext_vector_type(8))) short bf16x8;
typedef __attribute__((ext_vector_type(4))) float f32x4;

DINL float fast_exp2(float x) { return __builtin_amdgcn_exp2f(x); }

DINL unsigned short f2bf(float f) {
  __hip_bfloat16 h = __float2bfloat16(f);
  unsigned short u;
  __builtin_memcpy(&u, &h, 2);
  return u;
}

// cheap round-half-up f32->bf16 (abs err <= 1 ulp; fine at 0.1 threshold)
DINL unsigned int bfbits(float f) {
  unsigned int u;
  __builtin_memcpy(&u, &f, 4);
  return (u + 0x8000u) >> 16;
}

DINL void gload_lds16(const void* g, void* l) {
  // 16B per lane; LDS dest = wave-uniform base + lane*16
  __builtin_amdgcn_global_load_lds((__attribute__((address_space(1))) void*)g,
                                   (__attribute__((address_space(3))) void*)l,
                                   16, 0, 0);
}

// ---------------- LayerNorm (fp32 -> bf16) ----------------
__global__ __launch_bounds__(256)
void ln_kernel(const float* __restrict__ x, const float* __restrict__ gamma,
               const float* __restrict__ beta, unsigned short* __restrict__ h) {
  __shared__ float red[8];
  int row = blockIdx.x;          // 0..4095
  int t = threadIdx.x;           // 0..255, 4 floats each
  float4 v = reinterpret_cast<const float4*>(x + (size_t)row * 1024)[t];
  float s  = v.x + v.y + v.z + v.w;
  float sq = v.x*v.x + v.y*v.y + v.z*v.z + v.w*v.w;
#pragma unroll
  for (int off = 1; off < 64; off <<= 1) {
    s  += __shfl_xor(s, off);
    sq += __shfl_xor(sq, off);
  }
  int wid = t >> 6;
  if ((t & 63) == 0) { red[wid] = s; red[4 + wid] = sq; }
  __syncthreads();
  s  = red[0] + red[1] + red[2] + red[3];
  sq = red[4] + red[5] + red[6] + red[7];
  float mu   = s * (1.0f / 1024.0f);
  float var  = sq * (1.0f / 1024.0f) - mu * mu;
  float rstd = rsqrtf(var + 1e-5f);
  float4 g = reinterpret_cast<const float4*>(gamma)[t];
  float4 b = reinterpret_cast<const float4*>(beta)[t];
  ushort4 o;
  o.x = f2bf((v.x - mu) * rstd * g.x + b.x);
  o.y = f2bf((v.y - mu) * rstd * g.y + b.y);
  o.z = f2bf((v.z - mu) * rstd * g.z + b.z);
  o.w = f2bf((v.w - mu) * rstd * g.w + b.w);
  reinterpret_cast<ushort4*>(h + (size_t)row * 1024)[t] = o;
}

// ---------------- Transpose + cast: src fp32 [R,C] -> dst bf16 [C,R] ----------------
__global__ __launch_bounds__(256)
void transpose_cast_kernel(const float* __restrict__ src, unsigned short* __restrict__ dst,
                           int R, int C) {
  __shared__ float tile[32][33];
  int tx = threadIdx.x & 31, ty = threadIdx.x >> 5;  // 32 x 8
  int c0 = blockIdx.x * 32, r0 = blockIdx.y * 32;
#pragma unroll
  for (int i = 0; i < 4; i++)
    tile[ty + i * 8][tx] = src[(size_t)(r0 + ty + i * 8) * C + c0 + tx];
  __syncthreads();
#pragma unroll
  for (int i = 0; i < 4; i++) {
    int r = ty + i * 8;
    dst[(size_t)(c0 + r) * R + r0 + tx] = f2bf(tile[tx][r]);
  }
}

// ---------------- GEMM: C[M,N] = A[M,K] * Bt[N,K]^T (+epilogue) ----------------
// 128x128 tile, BK=64, 256 threads = 4 waves (2x2 of 64x64), 16x16x32 MFMA.
// LDS kb-major: chunk c = kb*128 + row holds 8 bf16 of row `row`, k-slice kb.
// MODE 0: qkv epilogue (bias, split q/k/vT, q scaled). MODE 1: bias+residual fp32 out.
template <int MODE>
__global__ __launch_bounds__(256)
void gemm128(const unsigned short* __restrict__ A,
             const unsigned short* __restrict__ Bt,
             int K,
             const float* __restrict__ bias,
             unsigned short* __restrict__ qdst, unsigned short* __restrict__ kdst,
             unsigned short* __restrict__ vTdst,
             const float* __restrict__ xres, float* __restrict__ out) {
  __shared__ unsigned short As[8192];  // 16 KB
  __shared__ unsigned short Bs[8192];
  int tid = threadIdx.x, wid = tid >> 6, lane = tid & 63;
  int l15 = lane & 15, l4 = lane >> 4;
  int brow = blockIdx.y * 128, bcol = blockIdx.x * 128;
  int wr = wid >> 1, wc = wid & 1;
  f32x4 acc[4][4] = {};

  for (int kt = 0; kt < K; kt += 64) {
    __syncthreads();
#pragma unroll
    for (int r = 0; r < 4; r++) {
      int c  = wid * 256 + r * 64;   // wave-uniform chunk base
      int cl = c + lane;
      int kb = cl >> 7, row = cl & 127;
      gload_lds16(A  + (size_t)(brow + row) * K + kt + kb * 8, As + c * 8);
      gload_lds16(Bt + (size_t)(bcol + row) * K + kt + kb * 8, Bs + c * 8);
    }
    __syncthreads();
#pragma unroll
    for (int ks = 0; ks < 2; ks++) {
      int kb = ks * 4 + l4;
      bf16x8 af[4], bfr[4];
#pragma unroll
      for (int m = 0; m < 4; m++)
        af[m] = *reinterpret_cast<const bf16x8*>(As + (kb * 128 + wr * 64 + m * 16 + l15) * 8);
#pragma unroll
      for (int n = 0; n < 4; n++)
        bfr[n] = *reinterpret_cast<const bf16x8*>(Bs + (kb * 128 + wc * 64 + n * 16 + l15) * 8);
#pragma unroll
      for (int m = 0; m < 4; m++)
#pragma unroll
        for (int n = 0; n < 4; n++)
          acc[m][n] = __builtin_amdgcn_mfma_f32_16x16x32_bf16(af[m], bfr[n], acc[m][n], 0, 0, 0);
    }
  }

  if (MODE == 0) {
    int sec = bcol >> 10;            // 0=q, 1=k, 2=v  (128-wide tiles never straddle)
    int secbase = sec << 10;
#pragma unroll
    for (int m = 0; m < 4; m++) {
      int row0 = brow + wr * 64 + m * 16 + l4 * 4;
      int b = row0 >> 11, t0 = row0 & 2047;
#pragma unroll
      for (int n = 0; n < 4; n++) {
        int col = (bcol & 1023) + wc * 64 + n * 16 + l15;
        float bv = bias[secbase + col];
        int hh = col >> 6, d = col & 63;
        if (sec == 2) {
          ushort4 pk;
          pk.x = f2bf(acc[m][n][0] + bv);
          pk.y = f2bf(acc[m][n][1] + bv);
          pk.z = f2bf(acc[m][n][2] + bv);
          pk.w = f2bf(acc[m][n][3] + bv);
          *reinterpret_cast<ushort4*>(vTdst + ((size_t)(b * 16 + hh) * 64 + d) * 2048 + t0) = pk;
        } else {
          unsigned short* dst = (sec == 0) ? qdst : kdst;
          // q pre-scaled by 1/sqrt(hd) * log2(e) so attention can use exp2
          float sc = (sec == 0) ? 0.125f * 1.44269504088896f : 1.0f;
#pragma unroll
          for (int j = 0; j < 4; j++)
            dst[((size_t)(b * 16 + hh) * 2048 + t0 + j) * 64 + d] = f2bf((acc[m][n][j] + bv) * sc);
        }
      }
    }
  } else {
#pragma unroll
    for (int m = 0; m < 4; m++) {
      int row0 = brow + wr * 64 + m * 16 + l4 * 4;
#pragma unroll
      for (int n = 0; n < 4; n++) {
        int col = bcol + wc * 64 + n * 16 + l15;
        float bv = bias[col];
#pragma unroll
        for (int j = 0; j < 4; j++) {
          size_t idx = (size_t)(row0 + j) * 1024 + col;
          out[idx] = acc[m][n][j] + bv + xres[idx];
        }
      }
    }
  }
}

// ---------------- Flash attention (swapped-operand, transposed PV) ----------------
// 512 blocks (XCD-chunked), 4 waves x 32 q-rows = 128 q-rows/block.
// KV rounds of 128 keys (two 64-key sub-tiles) -> 16 barriers total.
// S^T = mfma(A=K, B=Q): lane owns q-row l15 (x2 m-blocks), 16 keys -> in-reg tree
// + 2 shfl for max only. l-sum kept as PER-LANE PARTIALS (rescale factor is
// row-uniform) and reduced once in the epilogue. Defer-max (T13, THR=11 log2):
// skip rescale when __all(mx <= mst+11). O^T = mfma(A=V^T, B=P^T): V-frags read
// DIRECT from global vT (L2-resident); sub0's V issued BEFORE the K-prefetch so
// PV's vmcnt wait doesn't drain it. K staged in LDS (dbuf, XOR-swizzled).
__global__ __launch_bounds__(256, 2)
void attn_kernel(const unsigned short* __restrict__ q,
                 const unsigned short* __restrict__ kk,
                 const unsigned short* __restrict__ vT,
                 unsigned short* __restrict__ o) {
  const int T = 2048;
  __shared__ unsigned short Ks[2][8192];   // 32 KB: 128 keys x 8 d-chunks (^key&7)
  __shared__ unsigned short Ps[4][2048];   // 16 KB: per-wave [q 32][key 64 ^ (q&7)<<3]
  int tid = threadIdx.x, wid = tid >> 6, lane = tid & 63;
  int l15 = lane & 15, l4 = lane >> 4;
  int swz = (l15 & 7) << 3;                // Ps XOR swizzle for this lane's q-row

  // XCD-chunked bijective remap: all 16 q-blocks of a head land on one XCD
  int lin = blockIdx.x;                    // 0..511
  int rl  = (lin & 7) * 64 + (lin >> 3);
  int bx = rl & 15, bh = rl >> 4;
  int q0 = bx * 128 + wid * 32;            // wave's 32 q-rows

  const unsigned short* qh = q  + (size_t)bh * T * 64;
  const unsigned short* kh = kk + (size_t)bh * T * 64;
  const unsigned short* vh = vT + (size_t)bh * 64 * T;

  // Q B-fragments: lane holds Q[q = q0 + m*16 + l15][d = ks*32 + l4*8 ..+8]
  bf16x8 qf[2][2];
#pragma unroll
  for (int m = 0; m < 2; m++)
#pragma unroll
    for (int ks = 0; ks < 2; ks++)
      qf[m][ks] = *reinterpret_cast<const bf16x8*>(
          qh + (size_t)(q0 + m * 16 + l15) * 64 + ks * 32 + l4 * 8);

  f32x4 accO[2][4] = {};                   // O^T[d = n*16+l4*4+j][q = l15 + 16m]
  float mst[2] = {-1e30f, -1e30f}, lst[2] = {0.0f, 0.0f};  // lst = per-lane partial

  // stage 128 keys (coalesced 128B rows, d-chunk pre-swizzled by key&7)
#define STAGE128(buf, kv0)                                                     \
  {                                                                            \
    _Pragma("unroll") for (int r = 0; r < 4; r++) {                            \
      int c  = (wid * 4 + r) * 64;                                             \
      int cl = c + lane;                                                       \
      int key = cl >> 3;                                                       \
      int kb  = (cl & 7) ^ (key & 7);                                          \
      gload_lds16(kh + (size_t)((kv0) + key) * 64 + kb * 8, &Ks[buf][c * 8]);  \
    }                                                                          \
  }

  // one 64-key sub-tile: QK -> softmax(defer-max) -> PV
#define SUBTILE(sub, vf)                                                       \
  {                                                                            \
    f32x4 s[2][4] = {};                                                        \
    __builtin_amdgcn_s_setprio(1);                                             \
    _Pragma("unroll") for (int ks = 0; ks < 2; ks++) {                         \
      _Pragma("unroll") for (int n = 0; n < 4; n++) {                          \
        int kkey = (sub) * 64 + n * 16 + l15;                                  \
        int slot = kkey * 8 + ((ks * 4 + l4) ^ (kkey & 7));                    \
        bf16x8 kf = *reinterpret_cast<const bf16x8*>(&Ks[cur][slot * 8]);      \
        _Pragma("unroll") for (int m = 0; m < 2; m++)                          \
          s[m][n] = __builtin_amdgcn_mfma_f32_16x16x32_bf16(kf, qf[m][ks],     \
                                                            s[m][n], 0, 0, 0); \
      }                                                                        \
    }                                                                          \
    __builtin_amdgcn_s_setprio(0);                                             \
    float mx[2];                                                               \
    _Pragma("unroll") for (int m = 0; m < 2; m++) {                            \
      float a0 = fmaxf(fmaxf(s[m][0][0], s[m][0][1]),                          \
                       fmaxf(s[m][0][2], s[m][0][3]));                         \
      float a1 = fmaxf(fmaxf(s[m][1][0], s[m][1][1]),                          \
                       fmaxf(s[m][1][2], s[m][1][3]));                         \
      float a2 = fmaxf(fmaxf(s[m][2][0], s[m][2][1]),                          \
                       fmaxf(s[m][2][2], s[m][2][3]));                         \
      float a3 = fmaxf(fmaxf(s[m][3][0], s[m][3][1]),                          \
                       fmaxf(s[m][3][2], s[m][3][3]));                         \
      float mxv = fmaxf(fmaxf(a0, a1), fmaxf(a2, a3));                         \
      mxv = fmaxf(mxv, __shfl_xor(mxv, 16));                                   \
      mxv = fmaxf(mxv, __shfl_xor(mxv, 32));                                   \
      mx[m] = mxv;                                                             \
    }                                                                          \
    int defer = (mx[0] <= mst[0] + 11.0f) && (mx[1] <= mst[1] + 11.0f);        \
    if (__all(defer)) {                                                        \
      _Pragma("unroll") for (int m = 0; m < 2; m++) {                          \
        float sum = 0.0f;                                                      \
        _Pragma("unroll") for (int n = 0; n < 4; n++) {                        \
          _Pragma("unroll") for (int j = 0; j < 4; j++) {                      \
            float p = fast_exp2(s[m][n][j] - mst[m]);                          \
            s[m][n][j] = p;                                                    \
            sum += p;                                                          \
          }                                                                    \
          unsigned int u0 = bfbits(s[m][n][0]) | (bfbits(s[m][n][1]) << 16);   \
          unsigned int u1 = bfbits(s[m][n][2]) | (bfbits(s[m][n][3]) << 16);   \
          *reinterpret_cast<uint2*>(                                           \
              &Ps[wid][(m * 16 + l15) * 64 + ((n * 16 + l4 * 4) ^ swz)]) =     \
              make_uint2(u0, u1);                                              \
        }                                                                      \
        lst[m] += sum;                                                         \
      }                                                                        \
    } else {                                                                   \
      _Pragma("unroll") for (int m = 0; m < 2; m++) {                          \
        float mnew = fmaxf(mst[m], mx[m]);                                     \
        float a = fast_exp2(mst[m] - mnew);                                    \
        float sum = 0.0f;                                                      \
        _Pragma("unroll") for (int n = 0; n < 4; n++) {                        \
          _Pragma("unroll") for (int j = 0; j < 4; j++) {                      \
            float p = fast_exp2(s[m][n][j] - mnew);                            \
            s[m][n][j] = p;                                                    \
            sum += p;                                                          \
          }                                                                    \
          unsigned int u0 = bfbits(s[m][n][0]) | (bfbits(s[m][n][1]) << 16);   \
          unsigned int u1 = bfbits(s[m][n][2]) | (bfbits(s[m][n][3]) << 16);   \
          *reinterpret_cast<uint2*>(                                           \
              &Ps[wid][(m * 16 + l15) * 64 + ((n * 16 + l4 * 4) ^ swz)]) =     \
              make_uint2(u0, u1);                                              \
        }                                                                      \
        lst[m] = lst[m] * a + sum;                                             \
        mst[m] = mnew;                                                         \
        _Pragma("unroll") for (int n = 0; n < 4; n++)                          \
          _Pragma("unroll") for (int j = 0; j < 4; j++) accO[m][n][j] *= a;    \
      }                                                                        \
    }                                                                          \
    _Pragma("unroll") for (int ks = 0; ks < 2; ks++) {                         \
      _Pragma("unroll") for (int m = 0; m < 2; m++) {                          \
        bf16x8 pf = *reinterpret_cast<const bf16x8*>(                          \
            &Ps[wid][(m * 16 + l15) * 64 + ((ks * 32 + l4 * 8) ^ swz)]);       \
        __builtin_amdgcn_s_setprio(1);                                         \
        _Pragma("unroll") for (int n = 0; n < 4; n++)                          \
          accO[m][n] = __builtin_amdgcn_mfma_f32_16x16x32_bf16(                \
              vf[ks][n], pf, accO[m][n], 0, 0, 0);                             \
        __builtin_amdgcn_s_setprio(0);                                         \
      }                                                                        \
    }                                                                          \
  }

#define LOADV(vf, kvs)                                                         \
  {                                                                            \
    _Pragma("unroll") for (int ks = 0; ks < 2; ks++)                           \
      _Pragma("unroll") for (int n = 0; n < 4; n++)                            \
        vf[ks][n] = *reinterpret_cast<const bf16x8*>(                          \
            vh + (size_t)(n * 16 + l15) * T + (kvs) + ks * 32 + l4 * 8);       \
  }

  STAGE128(0, 0);
  __syncthreads();
  int cur = 0;

  for (int kv0 = 0; kv0 < T; kv0 += 128) {
    // sub0 V first (so PV0's vmcnt wait keeps the K-prefetch in flight)
    bf16x8 vf0[2][4];
    LOADV(vf0, kv0);
    if (kv0 + 128 < T) STAGE128(cur ^ 1, kv0 + 128);
    SUBTILE(0, vf0);
    // sub1 V: covered by sub1's QK+softmax; draining STAGE here is harmless
    // (STAGE has had all of sub0's compute time to complete)
    bf16x8 vf1[2][4];
    LOADV(vf1, kv0 + 64);
    SUBTILE(1, vf1);
    __syncthreads();
    cur ^= 1;
  }
#undef SUBTILE
#undef LOADV
#undef STAGE128

  int b = bh >> 4, hh = bh & 15;
#pragma unroll
  for (int m = 0; m < 2; m++) {
    // reduce the per-lane partial l across the 4 lane-groups of the row
    float l = lst[m];
    l += __shfl_xor(l, 16);
    l += __shfl_xor(l, 32);
    float inv = 1.0f / l;
    int row = q0 + m * 16 + l15;
#pragma unroll
    for (int n = 0; n < 4; n++) {
      ushort4 pk;
      pk.x = f2bf(accO[m][n][0] * inv);
      pk.y = f2bf(accO[m][n][1] * inv);
      pk.z = f2bf(accO[m][n][2] * inv);
      pk.w = f2bf(accO[m][n][3] * inv);
      *reinterpret_cast<ushort4*>(
          &o[(size_t)(b * 2048 + row) * 1024 + hh * 64 + n * 16 + l4 * 4]) = pk;
    }
  }
}

extern "C" void kernel_launch(void* const* d_in, const int* in_sizes, int n_in,
                              void* d_out, int out_size, void* d_ws, size_t ws_size,
                              hipStream_t stream) {
  const float* x     = (const float*)d_in[0];
  const float* W_qkv = (const float*)d_in[1];
  const float* b_qkv = (const float*)d_in[2];
  const float* W_out = (const float*)d_in[3];
  const float* b_out = (const float*)d_in[4];
  const float* gamma = (const float*)d_in[5];
  const float* beta  = (const float*)d_in[6];
  float* out = (float*)d_out;

  char* ws = (char*)d_ws;
  unsigned short* h     = (unsigned short*)(ws);
  unsigned short* WqkvT = (unsigned short*)(ws + (size_t)(8)  * 1024 * 1024);
  unsigned short* WoutT = (unsigned short*)(ws + (size_t)(14) * 1024 * 1024);
  unsigned short* qb    = (unsigned short*)(ws + (size_t)(16) * 1024 * 1024);
  unsigned short* kb    = (unsigned short*)(ws + (size_t)(24) * 1024 * 1024);
  unsigned short* vTb   = (unsigned short*)(ws + (size_t)(32) * 1024 * 1024);
  unsigned short* attno = (unsigned short*)(ws + (size_t)(40) * 1024 * 1024);

  ln_kernel<<<4096, 256, 0, stream>>>(x, gamma, beta, h);
  transpose_cast_kernel<<<dim3(96, 32), 256, 0, stream>>>(W_qkv, WqkvT, 1024, 3072);
  transpose_cast_kernel<<<dim3(32, 32), 256, 0, stream>>>(W_out, WoutT, 1024, 1024);
  gemm128<0><<<dim3(24, 32), 256, 0, stream>>>(h, WqkvT, 1024, b_qkv, qb, kb, vTb, nullptr, nullptr);
  attn_kernel<<<512, 256, 0, stream>>>(qb, kb, vTb, attno);
  gemm128<1><<<dim3(8, 32), 256, 0, stream>>>(attno, WoutT, 1024, b_out, nullptr, nullptr, nullptr, x, out);
}